// Round 1
// baseline (696.186 us; speedup 1.0000x reference)
//
#include <hip/hip_runtime.h>
#include <math.h>

// Problem constants
#define BB 2
#define HH 64
#define WW 64
#define CC 128
#define NHD 4
#define HD 32
#define KS 7
#define KK 49
#define HID 512
#define NT (BB*HH*WW)   // 8192 tokens

// ---------------- LayerNorm: one wave (64 threads) per row of 128 ----------------
__global__ void ln_kernel(const float* __restrict__ x, const float* __restrict__ g,
                          const float* __restrict__ b, float* __restrict__ y) {
    int row = blockIdx.x;
    int lane = threadIdx.x;            // 0..63
    const float* xr = x + (size_t)row * CC;
    float v0 = xr[lane];
    float v1 = xr[lane + 64];
    float s = v0 + v1;
    #pragma unroll
    for (int off = 32; off > 0; off >>= 1) s += __shfl_down(s, off);
    s = __shfl(s, 0);
    float mean = s * (1.0f / CC);
    float d0 = v0 - mean, d1 = v1 - mean;
    float vs = d0 * d0 + d1 * d1;
    #pragma unroll
    for (int off = 32; off > 0; off >>= 1) vs += __shfl_down(vs, off);
    vs = __shfl(vs, 0);
    float rstd = rsqrtf(vs * (1.0f / CC) + 1e-5f);
    float* yr = y + (size_t)row * CC;
    yr[lane]      = d0 * rstd * g[lane]      + b[lane];
    yr[lane + 64] = d1 * rstd * g[lane + 64] + b[lane + 64];
}

// ---------------- Generic GEMM: out = A(MxK) @ W(KxN) + bias [+gelu] [+resid] ----
__global__ void gemm_kernel(const float* __restrict__ A, const float* __restrict__ Wm,
                            const float* __restrict__ bias, const float* __restrict__ resid,
                            float* __restrict__ out, int M, int N, int K, int do_gelu) {
    int idx = blockIdx.x * blockDim.x + threadIdx.x;
    if (idx >= M * N) return;
    int m = idx / N;
    int n = idx - m * N;
    const float* a = A + (size_t)m * K;
    float acc = bias[n];
    for (int k = 0; k < K; ++k) acc += a[k] * Wm[(size_t)k * N + n];
    if (do_gelu) acc = 0.5f * acc * (1.0f + erff(acc * 0.70710678118654752f));
    if (resid) acc += resid[idx];
    out[idx] = acc;
}

// ---------------- Neighborhood attention: one thread per (b,i,j,head) -----------
__global__ void nat_attn_kernel(const float* __restrict__ qkv, const float* __restrict__ rpb,
                                float* __restrict__ out) {
    int t = blockIdx.x * blockDim.x + threadIdx.x;
    if (t >= NT * NHD) return;
    int h   = t & (NHD - 1);
    int bij = t >> 2;                   // token index 0..8191
    int j   = bij & (WW - 1);
    int bi  = bij >> 6;
    int i   = bi & (HH - 1);
    int b   = bi >> 6;

    int si = i - KS / 2; si = si < 0 ? 0 : (si > HH - KS ? HH - KS : si);
    int sj = j - KS / 2; sj = sj < 0 ? 0 : (sj > WW - KS ? WW - KS : sj);

    const float* qp = qkv + (size_t)bij * (3 * CC) + h * HD;
    float q[HD];
    #pragma unroll
    for (int d = 0; d < HD; ++d) q[d] = qp[d] * 0.17677669529663687f;  // 1/sqrt(32)

    float sc[KK];
    float mx = -1e30f;
    #pragma unroll
    for (int a = 0; a < KS; ++a) {
        int ki = si + a;
        int ri = ki - i + (KS - 1);
        #pragma unroll
        for (int c = 0; c < KS; ++c) {
            int kj = sj + c;
            int rj = kj - j + (KS - 1);
            const float* kp = qkv + ((size_t)((b * HH + ki) * WW + kj)) * (3 * CC) + CC + h * HD;
            float dot = 0.0f;
            #pragma unroll
            for (int d = 0; d < HD; ++d) dot += q[d] * kp[d];
            dot += rpb[(h * 13 + ri) * 13 + rj];
            sc[a * KS + c] = dot;
            mx = fmaxf(mx, dot);
        }
    }
    float sum = 0.0f;
    #pragma unroll
    for (int p = 0; p < KK; ++p) { sc[p] = expf(sc[p] - mx); sum += sc[p]; }
    float inv = 1.0f / sum;

    float o[HD];
    #pragma unroll
    for (int d = 0; d < HD; ++d) o[d] = 0.0f;
    #pragma unroll
    for (int a = 0; a < KS; ++a) {
        int ki = si + a;
        #pragma unroll
        for (int c = 0; c < KS; ++c) {
            int kj = sj + c;
            const float* vp = qkv + ((size_t)((b * HH + ki) * WW + kj)) * (3 * CC) + 2 * CC + h * HD;
            float w = sc[a * KS + c] * inv;
            #pragma unroll
            for (int d = 0; d < HD; ++d) o[d] += w * vp[d];
        }
    }
    float* op = out + (size_t)bij * CC + h * HD;
    #pragma unroll
    for (int d = 0; d < HD; ++d) op[d] = o[d];
}

extern "C" void kernel_launch(void* const* d_in, const int* in_sizes, int n_in,
                              void* d_out, int out_size, void* d_ws, size_t ws_size,
                              hipStream_t stream) {
    const float* x       = (const float*)d_in[0];
    const float* norm1_g = (const float*)d_in[1];
    const float* norm1_b = (const float*)d_in[2];
    const float* qkv_w   = (const float*)d_in[3];
    const float* qkv_b   = (const float*)d_in[4];
    const float* rpb     = (const float*)d_in[5];
    const float* proj_w  = (const float*)d_in[6];
    const float* proj_b  = (const float*)d_in[7];
    const float* norm2_g = (const float*)d_in[8];
    const float* norm2_b = (const float*)d_in[9];
    const float* fc1_w   = (const float*)d_in[10];
    const float* fc1_b   = (const float*)d_in[11];
    const float* fc2_w   = (const float*)d_in[12];
    const float* fc2_b   = (const float*)d_in[13];
    float* out = (float*)d_out;

    char* ws = (char*)d_ws;
    // workspace layout (bytes):
    //   xn:       [0, 4MB)          -- LN1 output; dead after QKV GEMM
    //   qkv:      [4MB, 16.78MB)    -- dead after attention
    //   attn_out: [16.78MB, 20.97MB)-- dead after proj; reused for y (LN2 out)
    //   x1:       [20.97MB, 25.17MB)
    //   h1:       [0, 16.78MB)      -- reuses xn+qkv space
    float* xn       = (float*)(ws);
    float* qkv      = (float*)(ws + (size_t)4 * 1024 * 1024);
    float* attn_out = (float*)(ws + (size_t)16 * 1024 * 1024 + 768 * 1024);
    float* x1       = (float*)(ws + (size_t)20 * 1024 * 1024 + 992 * 1024);
    float* y        = attn_out;   // reuse after proj
    float* h1       = (float*)(ws);  // reuse xn+qkv region

    // 1) LN1
    ln_kernel<<<NT, 64, 0, stream>>>(x, norm1_g, norm1_b, xn);
    // 2) QKV GEMM: (8192x128)@(128x384)+b
    {
        int total = NT * 3 * CC;
        gemm_kernel<<<(total + 255) / 256, 256, 0, stream>>>(xn, qkv_w, qkv_b, nullptr, qkv,
                                                             NT, 3 * CC, CC, 0);
    }
    // 3) NAT attention
    {
        int total = NT * NHD;
        nat_attn_kernel<<<(total + 255) / 256, 256, 0, stream>>>(qkv, rpb, attn_out);
    }
    // 4) proj + bias + residual(x)
    {
        int total = NT * CC;
        gemm_kernel<<<(total + 255) / 256, 256, 0, stream>>>(attn_out, proj_w, proj_b, x, x1,
                                                             NT, CC, CC, 0);
    }
    // 5) LN2
    ln_kernel<<<NT, 64, 0, stream>>>(x1, norm2_g, norm2_b, y);
    // 6) FC1 + gelu
    {
        int total = NT * HID;
        gemm_kernel<<<(total + 255) / 256, 256, 0, stream>>>(y, fc1_w, fc1_b, nullptr, h1,
                                                             NT, HID, CC, 1);
    }
    // 7) FC2 + bias + residual(x1)
    {
        int total = NT * CC;
        gemm_kernel<<<(total + 255) / 256, 256, 0, stream>>>(h1, fc2_w, fc2_b, x1, out,
                                                             NT, CC, HID, 0);
    }
}

// Round 2
// 170.569 us; speedup vs baseline: 4.0815x; 4.0815x over previous
//
#include <hip/hip_runtime.h>
#include <hip/hip_bf16.h>
#include <math.h>

// Problem constants
#define BB 2
#define HH 64
#define WW 64
#define CC 128
#define NHD 4
#define HD 32
#define KS 7
#define KK 49
#define HID 512
#define NT (BB*HH*WW)   // 8192 tokens

typedef __attribute__((ext_vector_type(8))) short bf16x8;
typedef __attribute__((ext_vector_type(4))) float f32x4;

// ---------------- LayerNorm: one wave per row of 128; bf16 out + optional f32 out --
__global__ void ln_kernel_bf16(const float* __restrict__ x, const float* __restrict__ g,
                               const float* __restrict__ b, __hip_bfloat16* __restrict__ y) {
    int row = blockIdx.x;
    int lane = threadIdx.x;            // 0..63
    const float* xr = x + (size_t)row * CC;
    float v0 = xr[lane];
    float v1 = xr[lane + 64];
    float s = v0 + v1;
    #pragma unroll
    for (int off = 32; off > 0; off >>= 1) s += __shfl_down(s, off);
    s = __shfl(s, 0);
    float mean = s * (1.0f / CC);
    float d0 = v0 - mean, d1 = v1 - mean;
    float vs = d0 * d0 + d1 * d1;
    #pragma unroll
    for (int off = 32; off > 0; off >>= 1) vs += __shfl_down(vs, off);
    vs = __shfl(vs, 0);
    float rstd = rsqrtf(vs * (1.0f / CC) + 1e-5f);
    __hip_bfloat16* yr = y + (size_t)row * CC;
    yr[lane]      = __float2bfloat16(d0 * rstd * g[lane]      + b[lane]);
    yr[lane + 64] = __float2bfloat16(d1 * rstd * g[lane + 64] + b[lane + 64]);
}

// ---------------- weight cast + transpose: W[K][N] f32 -> Wt[N][K] bf16 ----------
__global__ void castT_kernel(const float* __restrict__ W, __hip_bfloat16* __restrict__ Wt,
                             int K, int N) {
    int idx = blockIdx.x * blockDim.x + threadIdx.x;
    if (idx >= K * N) return;
    int k = idx / N, n = idx - k * N;
    Wt[(size_t)n * K + k] = __float2bfloat16(W[idx]);
}

// ---------------- MFMA GEMM: out(MxN) = A(MxK,bf16) @ Wt(NxK,bf16)^T + bias ------
// block = 256 threads = 4 waves (2x2), tile 64x64; wave tile 32x32 via 16x16x32.
template<int OUT_BF16, int DO_GELU, int HAS_RESID>
__global__ void mfma_gemm(const __hip_bfloat16* __restrict__ A,
                          const __hip_bfloat16* __restrict__ Wt,
                          const float* __restrict__ bias,
                          const float* __restrict__ resid,
                          void* __restrict__ out,
                          int M, int N, int K) {
    int wid  = threadIdx.x >> 6;       // 0..3
    int lane = threadIdx.x & 63;
    int wr = wid >> 1, wc = wid & 1;
    int m0 = blockIdx.x * 64 + wr * 32;
    int n0 = blockIdx.y * 64 + wc * 32;
    int row = lane & 15;
    int kg  = lane >> 4;               // 0..3

    f32x4 acc[2][2] = {};
    for (int kk = 0; kk < K; kk += 32) {
        bf16x8 a[2], b[2];
        #pragma unroll
        for (int mi = 0; mi < 2; ++mi)
            a[mi] = *(const bf16x8*)(A + (size_t)(m0 + mi * 16 + row) * K + kk + kg * 8);
        #pragma unroll
        for (int ni = 0; ni < 2; ++ni)
            b[ni] = *(const bf16x8*)(Wt + (size_t)(n0 + ni * 16 + row) * K + kk + kg * 8);
        #pragma unroll
        for (int mi = 0; mi < 2; ++mi)
            #pragma unroll
            for (int ni = 0; ni < 2; ++ni)
                acc[mi][ni] = __builtin_amdgcn_mfma_f32_16x16x32_bf16(a[mi], b[ni], acc[mi][ni], 0, 0, 0);
    }
    // epilogue: D[row=(lane>>4)*4+r][col=lane&15]
    #pragma unroll
    for (int mi = 0; mi < 2; ++mi) {
        #pragma unroll
        for (int ni = 0; ni < 2; ++ni) {
            int col = n0 + ni * 16 + row;
            float bv = bias[col];
            #pragma unroll
            for (int r = 0; r < 4; ++r) {
                int rrow = m0 + mi * 16 + kg * 4 + r;
                float v = acc[mi][ni][r] + bv;
                if (DO_GELU) v = 0.5f * v * (1.0f + erff(v * 0.70710678118654752f));
                size_t off = (size_t)rrow * N + col;
                if (HAS_RESID) v += resid[off];
                if (OUT_BF16) ((__hip_bfloat16*)out)[off] = __float2bfloat16(v);
                else          ((float*)out)[off] = v;
            }
        }
    }
}

// ---------------- Neighborhood attention: one thread per (b,i,j,head) -----------
// reads fp32 qkv, writes bf16 attn output
__global__ void nat_attn_kernel(const float* __restrict__ qkv, const float* __restrict__ rpb,
                                __hip_bfloat16* __restrict__ out) {
    int t = blockIdx.x * blockDim.x + threadIdx.x;
    if (t >= NT * NHD) return;
    int h   = t & (NHD - 1);
    int bij = t >> 2;
    int j   = bij & (WW - 1);
    int bi  = bij >> 6;
    int i   = bi & (HH - 1);
    int b   = bi >> 6;

    int si = i - KS / 2; si = si < 0 ? 0 : (si > HH - KS ? HH - KS : si);
    int sj = j - KS / 2; sj = sj < 0 ? 0 : (sj > WW - KS ? WW - KS : sj);

    const float* qp = qkv + (size_t)bij * (3 * CC) + h * HD;
    float q[HD];
    #pragma unroll
    for (int d = 0; d < HD; ++d) q[d] = qp[d] * 0.17677669529663687f;  // 1/sqrt(32)

    float sc[KK];
    float mx = -1e30f;
    #pragma unroll
    for (int a = 0; a < KS; ++a) {
        int ki = si + a;
        int ri = ki - i + (KS - 1);
        #pragma unroll
        for (int c = 0; c < KS; ++c) {
            int kj = sj + c;
            int rj = kj - j + (KS - 1);
            const float* kp = qkv + ((size_t)((b * HH + ki) * WW + kj)) * (3 * CC) + CC + h * HD;
            float dot = 0.0f;
            #pragma unroll
            for (int d = 0; d < HD; ++d) dot += q[d] * kp[d];
            dot += rpb[(h * 13 + ri) * 13 + rj];
            sc[a * KS + c] = dot;
            mx = fmaxf(mx, dot);
        }
    }
    float sum = 0.0f;
    #pragma unroll
    for (int p = 0; p < KK; ++p) { sc[p] = __expf(sc[p] - mx); sum += sc[p]; }
    float inv = 1.0f / sum;

    float o[HD];
    #pragma unroll
    for (int d = 0; d < HD; ++d) o[d] = 0.0f;
    #pragma unroll
    for (int a = 0; a < KS; ++a) {
        int ki = si + a;
        #pragma unroll
        for (int c = 0; c < KS; ++c) {
            int kj = sj + c;
            const float* vp = qkv + ((size_t)((b * HH + ki) * WW + kj)) * (3 * CC) + 2 * CC + h * HD;
            float w = sc[a * KS + c] * inv;
            #pragma unroll
            for (int d = 0; d < HD; ++d) o[d] += w * vp[d];
        }
    }
    __hip_bfloat16* op = out + (size_t)bij * CC + h * HD;
    #pragma unroll
    for (int d = 0; d < HD; ++d) op[d] = __float2bfloat16(o[d]);
}

extern "C" void kernel_launch(void* const* d_in, const int* in_sizes, int n_in,
                              void* d_out, int out_size, void* d_ws, size_t ws_size,
                              hipStream_t stream) {
    const float* x       = (const float*)d_in[0];
    const float* norm1_g = (const float*)d_in[1];
    const float* norm1_b = (const float*)d_in[2];
    const float* qkv_w   = (const float*)d_in[3];
    const float* qkv_b   = (const float*)d_in[4];
    const float* rpb     = (const float*)d_in[5];
    const float* proj_w  = (const float*)d_in[6];
    const float* proj_b  = (const float*)d_in[7];
    const float* norm2_g = (const float*)d_in[8];
    const float* norm2_b = (const float*)d_in[9];
    const float* fc1_w   = (const float*)d_in[10];
    const float* fc1_b   = (const float*)d_in[11];
    const float* fc2_w   = (const float*)d_in[12];
    const float* fc2_b   = (const float*)d_in[13];
    float* out = (float*)d_out;

    char* ws = (char*)d_ws;
    // workspace layout (bytes):
    //   qkv   f32 : [0, 12582912)               dead after attention; reused by h1
    //   xn    bf16: [12582912, 14680064)
    //   attn  bf16: [14680064, 16777216)
    //   x1    f32 : [16777216, 20971520)
    //   y     bf16: [20971520, 23068672)
    //   wts   bf16: [23068672, 23461888)
    float* qkv = (float*)(ws);
    __hip_bfloat16* xn   = (__hip_bfloat16*)(ws + 12582912);
    __hip_bfloat16* attn = (__hip_bfloat16*)(ws + 14680064);
    float* x1            = (float*)(ws + 16777216);
    __hip_bfloat16* y    = (__hip_bfloat16*)(ws + 20971520);
    __hip_bfloat16* h1   = (__hip_bfloat16*)(ws);  // reuse qkv region (8 MB)
    __hip_bfloat16* qkv_wt = (__hip_bfloat16*)(ws + 23068672);             // 384x128
    __hip_bfloat16* proj_wt = qkv_wt + 384 * 128;                          // 128x128
    __hip_bfloat16* fc1_wt  = proj_wt + 128 * 128;                         // 512x128
    __hip_bfloat16* fc2_wt  = fc1_wt + 512 * 128;                          // 128x512

    // weight casts (small)
    castT_kernel<<<(128 * 384 + 255) / 256, 256, 0, stream>>>(qkv_w, qkv_wt, 128, 384);
    castT_kernel<<<(128 * 128 + 255) / 256, 256, 0, stream>>>(proj_w, proj_wt, 128, 128);
    castT_kernel<<<(128 * 512 + 255) / 256, 256, 0, stream>>>(fc1_w, fc1_wt, 128, 512);
    castT_kernel<<<(512 * 128 + 255) / 256, 256, 0, stream>>>(fc2_w, fc2_wt, 512, 128);

    // 1) LN1 -> bf16
    ln_kernel_bf16<<<NT, 64, 0, stream>>>(x, norm1_g, norm1_b, xn);
    // 2) QKV GEMM: (8192x128)@(128x384) -> f32
    {
        dim3 grid(NT / 64, 384 / 64);
        mfma_gemm<0, 0, 0><<<grid, 256, 0, stream>>>(xn, qkv_wt, qkv_b, nullptr, qkv,
                                                     NT, 3 * CC, CC);
    }
    // 3) NAT attention -> bf16
    nat_attn_kernel<<<(NT * NHD + 255) / 256, 256, 0, stream>>>(qkv, rpb, attn);
    // 4) proj + bias + residual(x) -> f32 x1
    {
        dim3 grid(NT / 64, CC / 64);
        mfma_gemm<0, 0, 1><<<grid, 256, 0, stream>>>(attn, proj_wt, proj_b, x, x1,
                                                     NT, CC, CC);
    }
    // 5) LN2 -> bf16
    ln_kernel_bf16<<<NT, 64, 0, stream>>>(x1, norm2_g, norm2_b, y);
    // 6) FC1 + gelu -> bf16
    {
        dim3 grid(NT / 64, HID / 64);
        mfma_gemm<1, 1, 0><<<grid, 256, 0, stream>>>(y, fc1_wt, fc1_b, nullptr, h1,
                                                     NT, HID, CC);
    }
    // 7) FC2 + bias + residual(x1) -> f32 out
    {
        dim3 grid(NT / 64, CC / 64);
        mfma_gemm<0, 0, 1><<<grid, 256, 0, stream>>>(h1, fc2_wt, fc2_b, x1, out,
                                                     NT, CC, HID);
    }
}

// Round 3
// 120.609 us; speedup vs baseline: 5.7722x; 1.4142x over previous
//
#include <hip/hip_runtime.h>
#include <hip/hip_bf16.h>
#include <math.h>

// Problem constants
#define BB 2
#define HH 64
#define WW 64
#define CC 128
#define NHD 4
#define HD 32
#define KS 7
#define KK 49
#define HID 512
#define NT (BB*HH*WW)   // 8192 tokens

typedef __attribute__((ext_vector_type(8))) short bf16x8;
typedef __attribute__((ext_vector_type(4))) float f32x4;

// ---------------- LayerNorm: one wave per row of 128 -> bf16 ----------------
__global__ void ln_kernel_bf16(const float* __restrict__ x, const float* __restrict__ g,
                               const float* __restrict__ b, __hip_bfloat16* __restrict__ y) {
    int row = blockIdx.x;
    int lane = threadIdx.x;            // 0..63
    const float* xr = x + (size_t)row * CC;
    float v0 = xr[lane];
    float v1 = xr[lane + 64];
    float s = v0 + v1;
    #pragma unroll
    for (int off = 32; off > 0; off >>= 1) s += __shfl_down(s, off);
    s = __shfl(s, 0);
    float mean = s * (1.0f / CC);
    float d0 = v0 - mean, d1 = v1 - mean;
    float vs = d0 * d0 + d1 * d1;
    #pragma unroll
    for (int off = 32; off > 0; off >>= 1) vs += __shfl_down(vs, off);
    vs = __shfl(vs, 0);
    float rstd = rsqrtf(vs * (1.0f / CC) + 1e-5f);
    __hip_bfloat16* yr = y + (size_t)row * CC;
    yr[lane]      = __float2bfloat16(d0 * rstd * g[lane]      + b[lane]);
    yr[lane + 64] = __float2bfloat16(d1 * rstd * g[lane + 64] + b[lane + 64]);
}

// ---------------- fused weight cast+transpose for all four weights ----------
// W[K][N] f32 -> Wt[N][K] bf16
__global__ void castT_all(const float* __restrict__ qkv_w, const float* __restrict__ proj_w,
                          const float* __restrict__ fc1_w, const float* __restrict__ fc2_w,
                          __hip_bfloat16* __restrict__ qkv_wt, __hip_bfloat16* __restrict__ proj_wt,
                          __hip_bfloat16* __restrict__ fc1_wt, __hip_bfloat16* __restrict__ fc2_wt) {
    int idx = blockIdx.x * blockDim.x + threadIdx.x;
    const float* W; __hip_bfloat16* Wt; int K, N, off;
    if (idx < 49152)       { W = qkv_w;  Wt = qkv_wt;  K = 128; N = 384; off = idx; }
    else if (idx < 65536)  { W = proj_w; Wt = proj_wt; K = 128; N = 128; off = idx - 49152; }
    else if (idx < 131072) { W = fc1_w;  Wt = fc1_wt;  K = 128; N = 512; off = idx - 65536; }
    else                   { W = fc2_w;  Wt = fc2_wt;  K = 512; N = 128; off = idx - 131072; }
    int k = off / N, n = off - k * N;
    Wt[(size_t)n * K + k] = __float2bfloat16(W[(size_t)k * N + n]);
}

// ---------------- MFMA GEMM: out(MxN) = A(MxK,bf16) @ Wt(NxK,bf16)^T + bias ------
template<int OUT_BF16, int DO_GELU, int HAS_RESID>
__global__ void mfma_gemm(const __hip_bfloat16* __restrict__ A,
                          const __hip_bfloat16* __restrict__ Wt,
                          const float* __restrict__ bias,
                          const float* __restrict__ resid,
                          void* __restrict__ out,
                          int M, int N, int K) {
    int wid  = threadIdx.x >> 6;       // 0..3
    int lane = threadIdx.x & 63;
    int wr = wid >> 1, wc = wid & 1;
    int m0 = blockIdx.x * 64 + wr * 32;
    int n0 = blockIdx.y * 64 + wc * 32;
    int row = lane & 15;
    int kg  = lane >> 4;               // 0..3

    f32x4 acc[2][2] = {};
    for (int kk = 0; kk < K; kk += 32) {
        bf16x8 a[2], b[2];
        #pragma unroll
        for (int mi = 0; mi < 2; ++mi)
            a[mi] = *(const bf16x8*)(A + (size_t)(m0 + mi * 16 + row) * K + kk + kg * 8);
        #pragma unroll
        for (int ni = 0; ni < 2; ++ni)
            b[ni] = *(const bf16x8*)(Wt + (size_t)(n0 + ni * 16 + row) * K + kk + kg * 8);
        #pragma unroll
        for (int mi = 0; mi < 2; ++mi)
            #pragma unroll
            for (int ni = 0; ni < 2; ++ni)
                acc[mi][ni] = __builtin_amdgcn_mfma_f32_16x16x32_bf16(a[mi], b[ni], acc[mi][ni], 0, 0, 0);
    }
    #pragma unroll
    for (int mi = 0; mi < 2; ++mi) {
        #pragma unroll
        for (int ni = 0; ni < 2; ++ni) {
            int col = n0 + ni * 16 + row;
            float bv = bias[col];
            #pragma unroll
            for (int r = 0; r < 4; ++r) {
                int rrow = m0 + mi * 16 + kg * 4 + r;
                float v = acc[mi][ni][r] + bv;
                if (DO_GELU) v = 0.5f * v * (1.0f + erff(v * 0.70710678118654752f));
                size_t off = (size_t)rrow * N + col;
                if (HAS_RESID) v += resid[off];
                if (OUT_BF16) ((__hip_bfloat16*)out)[off] = __float2bfloat16(v);
                else          ((float*)out)[off] = v;
            }
        }
    }
}

// ---------------- Neighborhood attention: one WAVE per (token, head) ------------
// lanes = (d in [0,32), g in {0,1}); half-wave g handles keys of parity g.
// Online softmax in registers; 25 unrolled key-pair iterations.
__global__ void nat_attn_wave(const float* __restrict__ qkv, const float* __restrict__ rpb,
                              __hip_bfloat16* __restrict__ out) {
    int h    = threadIdx.x >> 6;       // wave id = head
    int lane = threadIdx.x & 63;
    int d = lane & 31, g = lane >> 5;
    int bij = blockIdx.x;
    int j  = bij & (WW - 1);
    int bi = bij >> 6;
    int i  = bi & (HH - 1);
    int b  = bi >> 6;

    int si = i - KS / 2; si = si < 0 ? 0 : (si > HH - KS ? HH - KS : si);
    int sj = j - KS / 2; sj = sj < 0 ? 0 : (sj > WW - KS ? WW - KS : sj);

    float qv = qkv[(size_t)bij * (3 * CC) + h * HD + d] * 0.17677669529663687f;
    const float* rpb_h = rpb + h * 169;  // 13x13

    float m = -1e30f, l = 0.0f, o = 0.0f;
    #pragma unroll
    for (int kp = 0; kp < 25; ++kp) {
        const int k0 = 2 * kp, k1 = 2 * kp + 1;
        const int a0 = k0 / 7, c0 = k0 % 7;
        const int a1 = (k1 < KK) ? k1 / 7 : 6, c1 = (k1 < KK) ? k1 % 7 : 6;
        const bool has1 = (k1 < KK);
        int a = g ? a1 : a0;
        int c = g ? c1 : c0;
        int ki = si + a, kj = sj + c;
        const float* kvb = qkv + ((size_t)((b * HH + ki) * WW + kj)) * (3 * CC) + h * HD + d;
        float kval = kvb[CC];          // K
        float vval = kvb[2 * CC];      // V
        float pd = qv * kval;
        #pragma unroll
        for (int off = 1; off < 32; off <<= 1) pd += __shfl_xor(pd, off);
        float s = pd + rpb_h[(ki - i + 6) * 13 + (kj - j + 6)];
        if (g && !has1) s = -1e30f;
        float s_other = __shfl_xor(s, 32);
        float mnew = fmaxf(m, fmaxf(s, s_other));
        float scale = __expf(m - mnew);
        float p = __expf(s - mnew);
        l = l * scale + p + __shfl_xor(p, 32);
        o = o * scale + p * vval;
        m = mnew;
    }
    o += __shfl_xor(o, 32);
    o *= __frcp_rn(l);
    if (g == 0)
        out[(size_t)bij * CC + h * HD + d] = __float2bfloat16(o);
}

extern "C" void kernel_launch(void* const* d_in, const int* in_sizes, int n_in,
                              void* d_out, int out_size, void* d_ws, size_t ws_size,
                              hipStream_t stream) {
    const float* x       = (const float*)d_in[0];
    const float* norm1_g = (const float*)d_in[1];
    const float* norm1_b = (const float*)d_in[2];
    const float* qkv_w   = (const float*)d_in[3];
    const float* qkv_b   = (const float*)d_in[4];
    const float* rpb     = (const float*)d_in[5];
    const float* proj_w  = (const float*)d_in[6];
    const float* proj_b  = (const float*)d_in[7];
    const float* norm2_g = (const float*)d_in[8];
    const float* norm2_b = (const float*)d_in[9];
    const float* fc1_w   = (const float*)d_in[10];
    const float* fc1_b   = (const float*)d_in[11];
    const float* fc2_w   = (const float*)d_in[12];
    const float* fc2_b   = (const float*)d_in[13];
    float* out = (float*)d_out;

    char* ws = (char*)d_ws;
    // workspace layout (bytes):
    //   qkv   f32 : [0, 12582912)               dead after attention; reused by h1
    //   xn    bf16: [12582912, 14680064)
    //   attn  bf16: [14680064, 16777216)
    //   x1    f32 : [16777216, 20971520)
    //   y     bf16: [20971520, 23068672)
    //   wts   bf16: [23068672, ...)
    float* qkv = (float*)(ws);
    __hip_bfloat16* xn   = (__hip_bfloat16*)(ws + 12582912);
    __hip_bfloat16* attn = (__hip_bfloat16*)(ws + 14680064);
    float* x1            = (float*)(ws + 16777216);
    __hip_bfloat16* y    = (__hip_bfloat16*)(ws + 20971520);
    __hip_bfloat16* h1   = (__hip_bfloat16*)(ws);  // reuse qkv region (8 MB)
    __hip_bfloat16* qkv_wt  = (__hip_bfloat16*)(ws + 23068672);  // 384x128
    __hip_bfloat16* proj_wt = qkv_wt + 384 * 128;                // 128x128
    __hip_bfloat16* fc1_wt  = proj_wt + 128 * 128;               // 512x128
    __hip_bfloat16* fc2_wt  = fc1_wt + 512 * 128;                // 128x512

    // fused weight casts (196608 elements)
    castT_all<<<768, 256, 0, stream>>>(qkv_w, proj_w, fc1_w, fc2_w,
                                       qkv_wt, proj_wt, fc1_wt, fc2_wt);

    // 1) LN1 -> bf16
    ln_kernel_bf16<<<NT, 64, 0, stream>>>(x, norm1_g, norm1_b, xn);
    // 2) QKV GEMM: (8192x128)@(128x384) -> f32
    {
        dim3 grid(NT / 64, 384 / 64);
        mfma_gemm<0, 0, 0><<<grid, 256, 0, stream>>>(xn, qkv_wt, qkv_b, nullptr, qkv,
                                                     NT, 3 * CC, CC);
    }
    // 3) NAT attention -> bf16 (one wave per token-head)
    nat_attn_wave<<<NT, 256, 0, stream>>>(qkv, rpb, attn);
    // 4) proj + bias + residual(x) -> f32 x1
    {
        dim3 grid(NT / 64, CC / 64);
        mfma_gemm<0, 0, 1><<<grid, 256, 0, stream>>>(attn, proj_wt, proj_b, x, x1,
                                                     NT, CC, CC);
    }
    // 5) LN2 -> bf16
    ln_kernel_bf16<<<NT, 64, 0, stream>>>(x1, norm2_g, norm2_b, y);
    // 6) FC1 + gelu -> bf16
    {
        dim3 grid(NT / 64, HID / 64);
        mfma_gemm<1, 1, 0><<<grid, 256, 0, stream>>>(y, fc1_wt, fc1_b, nullptr, h1,
                                                     NT, HID, CC);
    }
    // 7) FC2 + bias + residual(x1) -> f32 out
    {
        dim3 grid(NT / 64, CC / 64);
        mfma_gemm<0, 0, 1><<<grid, 256, 0, stream>>>(h1, fc2_wt, fc2_b, x1, out,
                                                     NT, CC, HID);
    }
}

// Round 4
// 79.670 us; speedup vs baseline: 8.7384x; 1.5139x over previous
//
#include <hip/hip_runtime.h>
#include <hip/hip_bf16.h>
#include <math.h>

// Problem constants
#define BB 2
#define HH 64
#define WW 64
#define CC 128
#define NHD 4
#define HD 32
#define KS 7
#define KK 49
#define HID 512
#define NT (BB*HH*WW)   // 8192 tokens

typedef __attribute__((ext_vector_type(8))) short bf16x8;
typedef __attribute__((ext_vector_type(4))) float f32x4;

// ---------------- LayerNorm: one wave per row of 128 -> bf16 ----------------
__global__ void ln_kernel_bf16(const float* __restrict__ x, const float* __restrict__ g,
                               const float* __restrict__ b, __hip_bfloat16* __restrict__ y) {
    int row = blockIdx.x;
    int lane = threadIdx.x;            // 0..63
    const float* xr = x + (size_t)row * CC;
    float v0 = xr[lane];
    float v1 = xr[lane + 64];
    float s = v0 + v1;
    #pragma unroll
    for (int off = 32; off > 0; off >>= 1) s += __shfl_down(s, off);
    s = __shfl(s, 0);
    float mean = s * (1.0f / CC);
    float d0 = v0 - mean, d1 = v1 - mean;
    float vs = d0 * d0 + d1 * d1;
    #pragma unroll
    for (int off = 32; off > 0; off >>= 1) vs += __shfl_down(vs, off);
    vs = __shfl(vs, 0);
    float rstd = rsqrtf(vs * (1.0f / CC) + 1e-5f);
    __hip_bfloat16* yr = y + (size_t)row * CC;
    yr[lane]      = __float2bfloat16(d0 * rstd * g[lane]      + b[lane]);
    yr[lane + 64] = __float2bfloat16(d1 * rstd * g[lane + 64] + b[lane + 64]);
}

// ---------------- fused weight cast+transpose for all four weights ----------
// W[K][N] f32 -> Wt[N][K] bf16
__global__ void castT_all(const float* __restrict__ qkv_w, const float* __restrict__ proj_w,
                          const float* __restrict__ fc1_w, const float* __restrict__ fc2_w,
                          __hip_bfloat16* __restrict__ qkv_wt, __hip_bfloat16* __restrict__ proj_wt,
                          __hip_bfloat16* __restrict__ fc1_wt, __hip_bfloat16* __restrict__ fc2_wt) {
    int idx = blockIdx.x * blockDim.x + threadIdx.x;
    const float* W; __hip_bfloat16* Wt; int K, N, off;
    if (idx < 49152)       { W = qkv_w;  Wt = qkv_wt;  K = 128; N = 384; off = idx; }
    else if (idx < 65536)  { W = proj_w; Wt = proj_wt; K = 128; N = 128; off = idx - 49152; }
    else if (idx < 131072) { W = fc1_w;  Wt = fc1_wt;  K = 128; N = 512; off = idx - 65536; }
    else                   { W = fc2_w;  Wt = fc2_wt;  K = 512; N = 128; off = idx - 131072; }
    int k = off / N, n = off - k * N;
    Wt[(size_t)n * K + k] = __float2bfloat16(W[(size_t)k * N + n]);
}

// ---------------- MFMA GEMM: out(MxN) = A(MxK,bf16) @ Wt(NxK,bf16)^T + bias ------
template<int OUT_BF16, int DO_GELU, int HAS_RESID>
__global__ void mfma_gemm(const __hip_bfloat16* __restrict__ A,
                          const __hip_bfloat16* __restrict__ Wt,
                          const float* __restrict__ bias,
                          const float* __restrict__ resid,
                          void* __restrict__ out,
                          int M, int N, int K) {
    int wid  = threadIdx.x >> 6;       // 0..3
    int lane = threadIdx.x & 63;
    int wr = wid >> 1, wc = wid & 1;
    int m0 = blockIdx.x * 64 + wr * 32;
    int n0 = blockIdx.y * 64 + wc * 32;
    int row = lane & 15;
    int kg  = lane >> 4;               // 0..3

    f32x4 acc[2][2] = {};
    for (int kk = 0; kk < K; kk += 32) {
        bf16x8 a[2], b[2];
        #pragma unroll
        for (int mi = 0; mi < 2; ++mi)
            a[mi] = *(const bf16x8*)(A + (size_t)(m0 + mi * 16 + row) * K + kk + kg * 8);
        #pragma unroll
        for (int ni = 0; ni < 2; ++ni)
            b[ni] = *(const bf16x8*)(Wt + (size_t)(n0 + ni * 16 + row) * K + kk + kg * 8);
        #pragma unroll
        for (int mi = 0; mi < 2; ++mi)
            #pragma unroll
            for (int ni = 0; ni < 2; ++ni)
                acc[mi][ni] = __builtin_amdgcn_mfma_f32_16x16x32_bf16(a[mi], b[ni], acc[mi][ni], 0, 0, 0);
    }
    #pragma unroll
    for (int mi = 0; mi < 2; ++mi) {
        #pragma unroll
        for (int ni = 0; ni < 2; ++ni) {
            int col = n0 + ni * 16 + row;
            float bv = bias[col];
            #pragma unroll
            for (int r = 0; r < 4; ++r) {
                int rrow = m0 + mi * 16 + kg * 4 + r;
                float v = acc[mi][ni][r] + bv;
                if (DO_GELU) v = 0.5f * v * (1.0f + erff(v * 0.70710678118654752f));
                size_t off = (size_t)rrow * N + col;
                if (HAS_RESID) v += resid[off];
                if (OUT_BF16) ((__hip_bfloat16*)out)[off] = __float2bfloat16(v);
                else          ((float*)out)[off] = v;
            }
        }
    }
}

// ---------------- Neighborhood attention: one WAVE per (token, head) ------------
// lane = kq*8 + dg: kq in [0,8) = key slot, dg in [0,8) = dim group (float4).
// 7 iterations x 8 keys; dot reduce = 3 shfl over dg; softmax reduce = 3 shfl over kq.
__global__ void nat_attn_wave8(const float* __restrict__ qkv, const float* __restrict__ rpb,
                               __hip_bfloat16* __restrict__ out) {
    int h    = threadIdx.x >> 6;       // wave id = head
    int lane = threadIdx.x & 63;
    int kq = lane >> 3, dg = lane & 7;
    int bij = blockIdx.x;
    int j  = bij & (WW - 1);
    int bi = bij >> 6;
    int i  = bi & (HH - 1);
    int b  = bi >> 6;

    int si = i - 3; si = si < 0 ? 0 : (si > HH - KS ? HH - KS : si);
    int sj = j - 3; sj = sj < 0 ? 0 : (sj > WW - KS ? WW - KS : sj);
    int oi = si - i + 6;               // rpb row offset for a=0
    int oj = sj - j + 6;               // rpb col offset for c=0

    float4 q4 = *(const float4*)(qkv + (size_t)bij * (3 * CC) + h * HD + dg * 4);
    const float sc = 0.17677669529663687f;  // 1/sqrt(32)
    q4.x *= sc; q4.y *= sc; q4.z *= sc; q4.w *= sc;
    const float* rpb_h = rpb + h * 169;     // 13x13

    float s[7];
    float4 v4[7];
    #pragma unroll
    for (int t = 0; t < 7; ++t) {
        int kk = t * 8 + kq;
        bool valid = kk < KK;
        int a = (kk * 37) >> 8;             // kk/7 for kk<56
        int c = kk - a * 7;
        if (!valid) { a = 0; c = 0; }
        int ki = si + a, kj = sj + c;
        const float* base = qkv + ((size_t)((b * HH + ki) * WW + kj)) * (3 * CC) + h * HD + dg * 4;
        float4 k4 = *(const float4*)(base + CC);
        v4[t]     = *(const float4*)(base + 2 * CC);
        float pd = q4.x * k4.x + q4.y * k4.y + q4.z * k4.z + q4.w * k4.w;
        pd += __shfl_xor(pd, 1);
        pd += __shfl_xor(pd, 2);
        pd += __shfl_xor(pd, 4);
        s[t] = valid ? (pd + rpb_h[(oi + a) * 13 + (oj + c)]) : -1e30f;
    }
    // max over this lane's 7 keys, then across the 8 kq groups (dg groups are replicas)
    float mx = s[0];
    #pragma unroll
    for (int t = 1; t < 7; ++t) mx = fmaxf(mx, s[t]);
    mx = fmaxf(mx, __shfl_xor(mx, 8));
    mx = fmaxf(mx, __shfl_xor(mx, 16));
    mx = fmaxf(mx, __shfl_xor(mx, 32));
    float l = 0.0f;
    #pragma unroll
    for (int t = 0; t < 7; ++t) { s[t] = __expf(s[t] - mx); l += s[t]; }
    l += __shfl_xor(l, 8);
    l += __shfl_xor(l, 16);
    l += __shfl_xor(l, 32);
    float inv = 1.0f / l;

    float4 o4 = make_float4(0.f, 0.f, 0.f, 0.f);
    #pragma unroll
    for (int t = 0; t < 7; ++t) {
        o4.x += s[t] * v4[t].x;
        o4.y += s[t] * v4[t].y;
        o4.z += s[t] * v4[t].z;
        o4.w += s[t] * v4[t].w;
    }
    #pragma unroll
    for (int off = 8; off <= 32; off <<= 1) {
        o4.x += __shfl_xor(o4.x, off);
        o4.y += __shfl_xor(o4.y, off);
        o4.z += __shfl_xor(o4.z, off);
        o4.w += __shfl_xor(o4.w, off);
    }
    if (kq == 0) {
        __hip_bfloat16 r0 = __float2bfloat16(o4.x * inv);
        __hip_bfloat16 r1 = __float2bfloat16(o4.y * inv);
        __hip_bfloat16 r2 = __float2bfloat16(o4.z * inv);
        __hip_bfloat16 r3 = __float2bfloat16(o4.w * inv);
        ushort4 u;
        u.x = *(unsigned short*)&r0;
        u.y = *(unsigned short*)&r1;
        u.z = *(unsigned short*)&r2;
        u.w = *(unsigned short*)&r3;
        *(ushort4*)(out + (size_t)bij * CC + h * HD + dg * 4) = u;
    }
}

extern "C" void kernel_launch(void* const* d_in, const int* in_sizes, int n_in,
                              void* d_out, int out_size, void* d_ws, size_t ws_size,
                              hipStream_t stream) {
    const float* x       = (const float*)d_in[0];
    const float* norm1_g = (const float*)d_in[1];
    const float* norm1_b = (const float*)d_in[2];
    const float* qkv_w   = (const float*)d_in[3];
    const float* qkv_b   = (const float*)d_in[4];
    const float* rpb     = (const float*)d_in[5];
    const float* proj_w  = (const float*)d_in[6];
    const float* proj_b  = (const float*)d_in[7];
    const float* norm2_g = (const float*)d_in[8];
    const float* norm2_b = (const float*)d_in[9];
    const float* fc1_w   = (const float*)d_in[10];
    const float* fc1_b   = (const float*)d_in[11];
    const float* fc2_w   = (const float*)d_in[12];
    const float* fc2_b   = (const float*)d_in[13];
    float* out = (float*)d_out;

    char* ws = (char*)d_ws;
    // workspace layout (bytes):
    //   qkv   f32 : [0, 12582912)               dead after attention; reused by h1
    //   xn    bf16: [12582912, 14680064)
    //   attn  bf16: [14680064, 16777216)
    //   x1    f32 : [16777216, 20971520)
    //   y     bf16: [20971520, 23068672)
    //   wts   bf16: [23068672, ...)
    float* qkv = (float*)(ws);
    __hip_bfloat16* xn   = (__hip_bfloat16*)(ws + 12582912);
    __hip_bfloat16* attn = (__hip_bfloat16*)(ws + 14680064);
    float* x1            = (float*)(ws + 16777216);
    __hip_bfloat16* y    = (__hip_bfloat16*)(ws + 20971520);
    __hip_bfloat16* h1   = (__hip_bfloat16*)(ws);  // reuse qkv region (8 MB)
    __hip_bfloat16* qkv_wt  = (__hip_bfloat16*)(ws + 23068672);  // 384x128
    __hip_bfloat16* proj_wt = qkv_wt + 384 * 128;                // 128x128
    __hip_bfloat16* fc1_wt  = proj_wt + 128 * 128;               // 512x128
    __hip_bfloat16* fc2_wt  = fc1_wt + 512 * 128;                // 128x512

    // fused weight casts (196608 elements)
    castT_all<<<768, 256, 0, stream>>>(qkv_w, proj_w, fc1_w, fc2_w,
                                       qkv_wt, proj_wt, fc1_wt, fc2_wt);

    // 1) LN1 -> bf16
    ln_kernel_bf16<<<NT, 64, 0, stream>>>(x, norm1_g, norm1_b, xn);
    // 2) QKV GEMM: (8192x128)@(128x384) -> f32
    {
        dim3 grid(NT / 64, 384 / 64);
        mfma_gemm<0, 0, 0><<<grid, 256, 0, stream>>>(xn, qkv_wt, qkv_b, nullptr, qkv,
                                                     NT, 3 * CC, CC);
    }
    // 3) NAT attention -> bf16 (one wave per token-head, 8-key x 8-dim lanes)
    nat_attn_wave8<<<NT, 256, 0, stream>>>(qkv, rpb, attn);
    // 4) proj + bias + residual(x) -> f32 x1
    {
        dim3 grid(NT / 64, CC / 64);
        mfma_gemm<0, 0, 1><<<grid, 256, 0, stream>>>(attn, proj_wt, proj_b, x, x1,
                                                     NT, CC, CC);
    }
    // 5) LN2 -> bf16
    ln_kernel_bf16<<<NT, 64, 0, stream>>>(x1, norm2_g, norm2_b, y);
    // 6) FC1 + gelu -> bf16
    {
        dim3 grid(NT / 64, HID / 64);
        mfma_gemm<1, 1, 0><<<grid, 256, 0, stream>>>(y, fc1_wt, fc1_b, nullptr, h1,
                                                     NT, HID, CC);
    }
    // 7) FC2 + bias + residual(x1) -> f32 out
    {
        dim3 grid(NT / 64, CC / 64);
        mfma_gemm<0, 0, 1><<<grid, 256, 0, stream>>>(h1, fc2_wt, fc2_b, x1, out,
                                                     NT, CC, HID);
    }
}

// Round 5
// 73.670 us; speedup vs baseline: 9.4500x; 1.0814x over previous
//
#include <hip/hip_runtime.h>
#include <hip/hip_bf16.h>
#include <math.h>

// Problem constants
#define BB 2
#define HH 64
#define WW 64
#define CC 128
#define NHD 4
#define HD 32
#define KS 7
#define KK 49
#define HID 512
#define NT (BB*HH*WW)   // 8192 tokens

typedef __attribute__((ext_vector_type(8))) short bf16x8;
typedef __attribute__((ext_vector_type(4))) float f32x4;

// ---------------- shared LN row helper: one wave per row of 128 -> bf16 ---------
__device__ __forceinline__ void ln_row(const float* __restrict__ xr, const float* __restrict__ g,
                                       const float* __restrict__ b, __hip_bfloat16* __restrict__ yr,
                                       int lane) {
    float v0 = xr[lane];
    float v1 = xr[lane + 64];
    float s = v0 + v1;
    #pragma unroll
    for (int off = 32; off > 0; off >>= 1) s += __shfl_down(s, off);
    s = __shfl(s, 0);
    float mean = s * (1.0f / CC);
    float d0 = v0 - mean, d1 = v1 - mean;
    float vs = d0 * d0 + d1 * d1;
    #pragma unroll
    for (int off = 32; off > 0; off >>= 1) vs += __shfl_down(vs, off);
    vs = __shfl(vs, 0);
    float rstd = rsqrtf(vs * (1.0f / CC) + 1e-5f);
    yr[lane]      = __float2bfloat16(d0 * rstd * g[lane]      + b[lane]);
    yr[lane + 64] = __float2bfloat16(d1 * rstd * g[lane + 64] + b[lane + 64]);
}

// ---------------- LN2: 4 rows per block (4 waves) ------------------------------
__global__ void ln_kernel_bf16(const float* __restrict__ x, const float* __restrict__ g,
                               const float* __restrict__ b, __hip_bfloat16* __restrict__ y) {
    int row = blockIdx.x * 4 + (threadIdx.x >> 6);
    int lane = threadIdx.x & 63;
    ln_row(x + (size_t)row * CC, g, b, y + (size_t)row * CC, lane);
}

// ---------------- prep: fused weight cast/transpose + LN1 ----------------------
// blocks [0,768): cast W[K][N] f32 -> Wt[N][K] bf16 ; blocks [768, 768+2048): LN1
__global__ void prep_kernel(const float* __restrict__ qkv_w, const float* __restrict__ proj_w,
                            const float* __restrict__ fc1_w, const float* __restrict__ fc2_w,
                            __hip_bfloat16* __restrict__ qkv_wt, __hip_bfloat16* __restrict__ proj_wt,
                            __hip_bfloat16* __restrict__ fc1_wt, __hip_bfloat16* __restrict__ fc2_wt,
                            const float* __restrict__ x, const float* __restrict__ norm1_g,
                            const float* __restrict__ norm1_b, __hip_bfloat16* __restrict__ xn) {
    if (blockIdx.x < 768) {
        int idx = blockIdx.x * 256 + threadIdx.x;
        const float* W; __hip_bfloat16* Wt; int K, N, off;
        if (idx < 49152)       { W = qkv_w;  Wt = qkv_wt;  K = 128; N = 384; off = idx; }
        else if (idx < 65536)  { W = proj_w; Wt = proj_wt; K = 128; N = 128; off = idx - 49152; }
        else if (idx < 131072) { W = fc1_w;  Wt = fc1_wt;  K = 128; N = 512; off = idx - 65536; }
        else                   { W = fc2_w;  Wt = fc2_wt;  K = 512; N = 128; off = idx - 131072; }
        int k = off / N, n = off - k * N;
        Wt[(size_t)n * K + k] = __float2bfloat16(W[(size_t)k * N + n]);
    } else {
        int row = (blockIdx.x - 768) * 4 + (threadIdx.x >> 6);
        int lane = threadIdx.x & 63;
        ln_row(x + (size_t)row * CC, norm1_g, norm1_b, xn + (size_t)row * CC, lane);
    }
}

// ---------------- MFMA GEMM: out(MxN) = A(MxK,bf16) @ Wt(NxK,bf16)^T + bias ------
// TK compile-time; unrolled in 128-wide K chunks (all loads up front, then 16 MFMA).
template<int TK, int OUT_BF16, int DO_GELU, int HAS_RESID>
__global__ void mfma_gemm(const __hip_bfloat16* __restrict__ A,
                          const __hip_bfloat16* __restrict__ Wt,
                          const float* __restrict__ bias,
                          const float* __restrict__ resid,
                          void* __restrict__ out,
                          int M, int N) {
    int wid  = threadIdx.x >> 6;       // 0..3
    int lane = threadIdx.x & 63;
    int wr = wid >> 1, wc = wid & 1;
    int m0 = blockIdx.x * 64 + wr * 32;
    int n0 = blockIdx.y * 64 + wc * 32;
    int row = lane & 15;
    int kg  = lane >> 4;               // 0..3

    f32x4 acc[2][2] = {};
    #pragma unroll
    for (int kc = 0; kc < TK; kc += 128) {
        bf16x8 a[2][4], b[2][4];
        #pragma unroll
        for (int mi = 0; mi < 2; ++mi)
            #pragma unroll
            for (int t = 0; t < 4; ++t)
                a[mi][t] = *(const bf16x8*)(A + (size_t)(m0 + mi * 16 + row) * TK + kc + t * 32 + kg * 8);
        #pragma unroll
        for (int ni = 0; ni < 2; ++ni)
            #pragma unroll
            for (int t = 0; t < 4; ++t)
                b[ni][t] = *(const bf16x8*)(Wt + (size_t)(n0 + ni * 16 + row) * TK + kc + t * 32 + kg * 8);
        #pragma unroll
        for (int t = 0; t < 4; ++t)
            #pragma unroll
            for (int mi = 0; mi < 2; ++mi)
                #pragma unroll
                for (int ni = 0; ni < 2; ++ni)
                    acc[mi][ni] = __builtin_amdgcn_mfma_f32_16x16x32_bf16(a[mi][t], b[ni][t], acc[mi][ni], 0, 0, 0);
    }
    #pragma unroll
    for (int mi = 0; mi < 2; ++mi) {
        #pragma unroll
        for (int ni = 0; ni < 2; ++ni) {
            int col = n0 + ni * 16 + row;
            float bv = bias[col];
            #pragma unroll
            for (int r = 0; r < 4; ++r) {
                int rrow = m0 + mi * 16 + kg * 4 + r;
                float v = acc[mi][ni][r] + bv;
                if (DO_GELU) v = 0.5f * v * (1.0f + erff(v * 0.70710678118654752f));
                size_t off = (size_t)rrow * N + col;
                if (HAS_RESID) v += resid[off];
                if (OUT_BF16) ((__hip_bfloat16*)out)[off] = __float2bfloat16(v);
                else          ((float*)out)[off] = v;
            }
        }
    }
}

// ---------------- Neighborhood attention (bf16 qkv): one WAVE per (token, head) --
// lane = kq*8 + dg: kq in [0,8) key slot, dg in [0,8) dim group (4 dims).
__device__ __forceinline__ float4 bf4_to_f4(ushort4 u) {
    float4 f;
    f.x = __uint_as_float((unsigned)u.x << 16);
    f.y = __uint_as_float((unsigned)u.y << 16);
    f.z = __uint_as_float((unsigned)u.z << 16);
    f.w = __uint_as_float((unsigned)u.w << 16);
    return f;
}

__global__ void nat_attn_wave8(const __hip_bfloat16* __restrict__ qkv,
                               const float* __restrict__ rpb,
                               __hip_bfloat16* __restrict__ out) {
    int h    = threadIdx.x >> 6;       // wave id = head
    int lane = threadIdx.x & 63;
    int kq = lane >> 3, dg = lane & 7;
    int bij = blockIdx.x;
    int j  = bij & (WW - 1);
    int bi = bij >> 6;
    int i  = bi & (HH - 1);
    int b  = bi >> 6;

    int si = i - 3; si = si < 0 ? 0 : (si > HH - KS ? HH - KS : si);
    int sj = j - 3; sj = sj < 0 ? 0 : (sj > WW - KS ? WW - KS : sj);
    int oi = si - i + 6;
    int oj = sj - j + 6;

    float4 q4 = bf4_to_f4(*(const ushort4*)(qkv + (size_t)bij * (3 * CC) + h * HD + dg * 4));
    const float sc = 0.17677669529663687f;  // 1/sqrt(32)
    q4.x *= sc; q4.y *= sc; q4.z *= sc; q4.w *= sc;
    const float* rpb_h = rpb + h * 169;     // 13x13

    float s[7];
    float4 v4[7];
    #pragma unroll
    for (int t = 0; t < 7; ++t) {
        int kk = t * 8 + kq;
        bool valid = kk < KK;
        int a = (kk * 37) >> 8;             // kk/7 for kk<56
        int c = kk - a * 7;
        if (!valid) { a = 0; c = 0; }
        int ki = si + a, kj = sj + c;
        const __hip_bfloat16* base = qkv + ((size_t)((b * HH + ki) * WW + kj)) * (3 * CC) + h * HD + dg * 4;
        float4 k4 = bf4_to_f4(*(const ushort4*)(base + CC));
        v4[t]     = bf4_to_f4(*(const ushort4*)(base + 2 * CC));
        float pd = q4.x * k4.x + q4.y * k4.y + q4.z * k4.z + q4.w * k4.w;
        pd += __shfl_xor(pd, 1);
        pd += __shfl_xor(pd, 2);
        pd += __shfl_xor(pd, 4);
        s[t] = valid ? (pd + rpb_h[(oi + a) * 13 + (oj + c)]) : -1e30f;
    }
    float mx = s[0];
    #pragma unroll
    for (int t = 1; t < 7; ++t) mx = fmaxf(mx, s[t]);
    mx = fmaxf(mx, __shfl_xor(mx, 8));
    mx = fmaxf(mx, __shfl_xor(mx, 16));
    mx = fmaxf(mx, __shfl_xor(mx, 32));
    float l = 0.0f;
    #pragma unroll
    for (int t = 0; t < 7; ++t) { s[t] = __expf(s[t] - mx); l += s[t]; }
    l += __shfl_xor(l, 8);
    l += __shfl_xor(l, 16);
    l += __shfl_xor(l, 32);
    float inv = 1.0f / l;

    float4 o4 = make_float4(0.f, 0.f, 0.f, 0.f);
    #pragma unroll
    for (int t = 0; t < 7; ++t) {
        o4.x += s[t] * v4[t].x;
        o4.y += s[t] * v4[t].y;
        o4.z += s[t] * v4[t].z;
        o4.w += s[t] * v4[t].w;
    }
    #pragma unroll
    for (int off = 8; off <= 32; off <<= 1) {
        o4.x += __shfl_xor(o4.x, off);
        o4.y += __shfl_xor(o4.y, off);
        o4.z += __shfl_xor(o4.z, off);
        o4.w += __shfl_xor(o4.w, off);
    }
    if (kq == 0) {
        __hip_bfloat16 r0 = __float2bfloat16(o4.x * inv);
        __hip_bfloat16 r1 = __float2bfloat16(o4.y * inv);
        __hip_bfloat16 r2 = __float2bfloat16(o4.z * inv);
        __hip_bfloat16 r3 = __float2bfloat16(o4.w * inv);
        ushort4 u;
        u.x = *(unsigned short*)&r0;
        u.y = *(unsigned short*)&r1;
        u.z = *(unsigned short*)&r2;
        u.w = *(unsigned short*)&r3;
        *(ushort4*)(out + (size_t)bij * CC + h * HD + dg * 4) = u;
    }
}

extern "C" void kernel_launch(void* const* d_in, const int* in_sizes, int n_in,
                              void* d_out, int out_size, void* d_ws, size_t ws_size,
                              hipStream_t stream) {
    const float* x       = (const float*)d_in[0];
    const float* norm1_g = (const float*)d_in[1];
    const float* norm1_b = (const float*)d_in[2];
    const float* qkv_w   = (const float*)d_in[3];
    const float* qkv_b   = (const float*)d_in[4];
    const float* rpb     = (const float*)d_in[5];
    const float* proj_w  = (const float*)d_in[6];
    const float* proj_b  = (const float*)d_in[7];
    const float* norm2_g = (const float*)d_in[8];
    const float* norm2_b = (const float*)d_in[9];
    const float* fc1_w   = (const float*)d_in[10];
    const float* fc1_b   = (const float*)d_in[11];
    const float* fc2_w   = (const float*)d_in[12];
    const float* fc2_b   = (const float*)d_in[13];
    float* out = (float*)d_out;

    char* ws = (char*)d_ws;
    // workspace layout (bytes):
    //   qkv   bf16: [0, 6291456)                dead after attention; reused by h1
    //   h1    bf16: [0, 8388608)                (FC1 out, reuses qkv region)
    //   xn    bf16: [12582912, 14680064)
    //   attn  bf16: [14680064, 16777216)
    //   x1    f32 : [16777216, 20971520)
    //   y     bf16: [20971520, 23068672)
    //   wts   bf16: [23068672, ...)
    __hip_bfloat16* qkv  = (__hip_bfloat16*)(ws);
    __hip_bfloat16* xn   = (__hip_bfloat16*)(ws + 12582912);
    __hip_bfloat16* attn = (__hip_bfloat16*)(ws + 14680064);
    float* x1            = (float*)(ws + 16777216);
    __hip_bfloat16* y    = (__hip_bfloat16*)(ws + 20971520);
    __hip_bfloat16* h1   = (__hip_bfloat16*)(ws);
    __hip_bfloat16* qkv_wt  = (__hip_bfloat16*)(ws + 23068672);  // 384x128
    __hip_bfloat16* proj_wt = qkv_wt + 384 * 128;                // 128x128
    __hip_bfloat16* fc1_wt  = proj_wt + 128 * 128;               // 512x128
    __hip_bfloat16* fc2_wt  = fc1_wt + 512 * 128;                // 128x512

    // 0) fused weight casts + LN1
    prep_kernel<<<768 + 2048, 256, 0, stream>>>(qkv_w, proj_w, fc1_w, fc2_w,
                                                qkv_wt, proj_wt, fc1_wt, fc2_wt,
                                                x, norm1_g, norm1_b, xn);
    // 1) QKV GEMM: (8192x128)@(128x384) -> bf16
    {
        dim3 grid(NT / 64, 384 / 64);
        mfma_gemm<128, 1, 0, 0><<<grid, 256, 0, stream>>>(xn, qkv_wt, qkv_b, nullptr, qkv,
                                                          NT, 3 * CC);
    }
    // 2) NAT attention -> bf16
    nat_attn_wave8<<<NT, 256, 0, stream>>>(qkv, rpb, attn);
    // 3) proj + bias + residual(x) -> f32 x1
    {
        dim3 grid(NT / 64, CC / 64);
        mfma_gemm<128, 0, 0, 1><<<grid, 256, 0, stream>>>(attn, proj_wt, proj_b, x, x1,
                                                          NT, CC);
    }
    // 4) LN2 -> bf16
    ln_kernel_bf16<<<NT / 4, 256, 0, stream>>>(x1, norm2_g, norm2_b, y);
    // 5) FC1 + gelu -> bf16
    {
        dim3 grid(NT / 64, HID / 64);
        mfma_gemm<128, 1, 1, 0><<<grid, 256, 0, stream>>>(y, fc1_wt, fc1_b, nullptr, h1,
                                                          NT, HID);
    }
    // 6) FC2 + bias + residual(x1) -> f32 out
    {
        dim3 grid(NT / 64, CC / 64);
        mfma_gemm<512, 0, 0, 1><<<grid, 256, 0, stream>>>(h1, fc2_wt, fc2_b, x1, out,
                                                          NT, CC);
    }
}